// Round 1
// baseline (2155.266 us; speedup 1.0000x reference)
//
#include <hip/hip_runtime.h>
#include <math.h>

#define NPROP 512
#define NB 2
#define NROWS (NB*NPROP)          // 1024
#define FCH 256
#define FH 64
#define FW 64
#define INDIM (FCH*7*7)           // 12544
#define HID 1024
#define NCLS 81
#define CAND_PER_IMG (NPROP*(NCLS-1))  // 40960
#define CLIPV 4.1351666f          // log(1000/16) rounded to f32

// ---- workspace layout (bytes) ----
#define X_OFF      0ull
#define H1_OFF     (X_OFF + (size_t)NROWS*INDIM*4)
#define H2_OFF     (H1_OFF + (size_t)NROWS*HID*4)
#define PROBS_OFF  (H2_OFF + (size_t)NROWS*HID*4)
#define CUR_OFF    (PROBS_OFF + (size_t)NROWS*NCLS*4)
#define CNT_OFF    (CUR_OFF + (size_t)NROWS*4*4)
#define CS_OFF     (CNT_OFF + 256)
#define CBX_OFF    (CS_OFF  + (size_t)NB*CAND_PER_IMG*4)
#define COB_OFF    (CBX_OFF + (size_t)NB*CAND_PER_IMG*16)
#define CAR_OFF    (COB_OFF + (size_t)NB*CAND_PER_IMG*16)
#define CLB_OFF    (CAR_OFF + (size_t)NB*CAND_PER_IMG*4)
#define CIX_OFF    (CLB_OFF + (size_t)NB*CAND_PER_IMG*4)

__global__ void init_kernel(int* cnt) {
    if (threadIdx.x < 2) cnt[threadIdx.x] = 0;
}

// one block per (b,n) proposal; 256 threads cover 256ch x 49 positions
__global__ __launch_bounds__(256) void roi_align_kernel(
    const float* __restrict__ feat, const float* __restrict__ boxes,
    float* __restrict__ X)
{
    int r = blockIdx.x;           // b*512+n
    int b = r >> 9;
    const float* f = feat + (size_t)b * (FCH*FH*FW);
    __shared__ float sb[4];
    __shared__ int   sx0[49], sx1[49], sy0[49], sy1[49];
    __shared__ float sw00[49], sw01[49], sw10[49], sw11[49];
    int tid = threadIdx.x;
    if (tid == 0) {
        float x1 = boxes[r*4+0]*0.125f, y1 = boxes[r*4+1]*0.125f;
        float x2 = boxes[r*4+2]*0.125f, y2 = boxes[r*4+3]*0.125f;
        sb[0] = x1; sb[1] = y1;
        sb[2] = fmaxf(x2-x1, 1.0f) / 7.0f;   // bw
        sb[3] = fmaxf(y2-y1, 1.0f) / 7.0f;   // bh
    }
    __syncthreads();
    if (tid < 49) {
        int py = tid / 7, px = tid - py*7;
        float gx = sb[0] + ((float)px + 0.5f)*sb[2];
        float gy = sb[1] + ((float)py + 0.5f)*sb[3];
        gx = fminf(fmaxf(gx, 0.0f), 63.0f);
        gy = fminf(fmaxf(gy, 0.0f), 63.0f);
        float x0f = floorf(gx), y0f = floorf(gy);
        int x0 = (int)x0f, y0 = (int)y0f;
        sx0[tid] = x0; sy0[tid] = y0;
        sx1[tid] = min(x0+1, 63); sy1[tid] = min(y0+1, 63);
        float dx = gx - x0f, dy = gy - y0f;
        sw00[tid] = (1.0f-dy)*(1.0f-dx);
        sw01[tid] = (1.0f-dy)*dx;
        sw10[tid] = dy*(1.0f-dx);
        sw11[tid] = dy*dx;
    }
    __syncthreads();
    size_t xbase = (size_t)r * INDIM;
    for (int i = tid; i < INDIM; i += 256) {
        int c = i / 49;
        int p = i - c*49;
        const float* fc = f + c*(FH*FW);
        int r0 = sy0[p]*FW, r1 = sy1[p]*FW;
        float v = fc[r0 + sx0[p]]*sw00[p] + fc[r0 + sx1[p]]*sw01[p]
                + fc[r1 + sx0[p]]*sw10[p] + fc[r1 + sx1[p]]*sw11[p];
        X[xbase + i] = v;
    }
}

// C[M x Nn] = relu(A[M x K] @ Bw[K x Nn] + bias), 64x64 tile, 4x4 microtile
__global__ __launch_bounds__(256) void sgemm_bias_relu(
    const float* __restrict__ A, const float* __restrict__ Bw,
    const float* __restrict__ bias, float* __restrict__ C,
    int K, int Nn, int do_relu)
{
    __shared__ float As[32][68];   // k-major, padded (272B rows: 16B aligned)
    __shared__ float Bs[32][68];
    int tid = threadIdx.x;
    int tx = tid & 15, ty = tid >> 4;
    int row0 = blockIdx.y * 64, col0 = blockIdx.x * 64;
    int ar = tid >> 3;            // 0..31
    int ak = (tid & 7) << 2;      // 0,4,..,28
    int bk = tid >> 4;            // 0..15
    int bn = (tid & 15) << 2;     // 0,4,..,60
    float acc[4][4];
#pragma unroll
    for (int i = 0; i < 4; ++i)
#pragma unroll
        for (int j = 0; j < 4; ++j) acc[i][j] = 0.f;

    for (int k0 = 0; k0 < K; k0 += 32) {
        float4 a0 = *(const float4*)&A[(size_t)(row0+ar   )*K + k0 + ak];
        float4 a1 = *(const float4*)&A[(size_t)(row0+ar+32)*K + k0 + ak];
        float4 b0 = *(const float4*)&Bw[(size_t)(k0+bk   )*Nn + col0 + bn];
        float4 b1 = *(const float4*)&Bw[(size_t)(k0+bk+16)*Nn + col0 + bn];
        __syncthreads();
        As[ak+0][ar] = a0.x; As[ak+1][ar] = a0.y; As[ak+2][ar] = a0.z; As[ak+3][ar] = a0.w;
        As[ak+0][ar+32] = a1.x; As[ak+1][ar+32] = a1.y; As[ak+2][ar+32] = a1.z; As[ak+3][ar+32] = a1.w;
        *(float4*)&Bs[bk   ][bn] = b0;
        *(float4*)&Bs[bk+16][bn] = b1;
        __syncthreads();
#pragma unroll
        for (int kk = 0; kk < 32; ++kk) {
            float4 av = *(const float4*)&As[kk][ty << 2];
            float4 bv = *(const float4*)&Bs[kk][tx << 2];
            float a4[4] = {av.x, av.y, av.z, av.w};
            float b4[4] = {bv.x, bv.y, bv.z, bv.w};
#pragma unroll
            for (int i = 0; i < 4; ++i)
#pragma unroll
                for (int j = 0; j < 4; ++j)
                    acc[i][j] = fmaf(a4[i], b4[j], acc[i][j]);
        }
    }
#pragma unroll
    for (int i = 0; i < 4; ++i) {
        int row = row0 + (ty << 2) + i;
        int col = col0 + (tx << 2);
        float4 o;
        o.x = acc[i][0] + bias[col+0];
        o.y = acc[i][1] + bias[col+1];
        o.z = acc[i][2] + bias[col+2];
        o.w = acc[i][3] + bias[col+3];
        if (do_relu) {
            o.x = fmaxf(o.x, 0.f); o.y = fmaxf(o.y, 0.f);
            o.z = fmaxf(o.z, 0.f); o.w = fmaxf(o.w, 0.f);
        }
        *(float4*)&C[(size_t)row*Nn + col] = o;
    }
}

// cls+bbox heads + decode (+softmax at last stage). 4 rows per block.
__global__ __launch_bounds__(512) void heads_kernel(
    const float* __restrict__ X, const float* __restrict__ cw, const float* __restrict__ cb,
    const float* __restrict__ bwt, const float* __restrict__ bbb,
    float* __restrict__ cur, float* __restrict__ probs,
    const int* __restrict__ img_sz, int stage, int write_probs)
{
    __shared__ float xs[4][1024];
    __shared__ float lg[4][96];
    int tid = threadIdx.x;
    int lr = tid >> 7;           // local row 0..3
    int j  = tid & 127;
    int row0 = blockIdx.x * 4;
    for (int i = tid; i < 4096; i += 512)
        xs[i >> 10][i & 1023] = X[(size_t)(row0 + (i >> 10))*1024 + (i & 1023)];
    __syncthreads();
    int row = row0 + lr;
    if (j < 81) {
        float acc = cb[j];
#pragma unroll 8
        for (int k = 0; k < 1024; ++k) acc = fmaf(xs[lr][k], cw[k*81 + j], acc);
        lg[lr][j] = acc;
    } else if (j < 85) {
        int jb = j - 81;
        float acc = bbb[jb];
#pragma unroll 8
        for (int k = 0; k < 1024; ++k) acc = fmaf(xs[lr][k], bwt[k*4 + jb], acc);
        lg[lr][j] = acc;
    }
    __syncthreads();
    if (j == 0) {   // box decode + clip
        float img = (float)(*img_sz);
        float px1 = cur[row*4+0], py1 = cur[row*4+1];
        float px2 = cur[row*4+2], py2 = cur[row*4+3];
        float pw = fmaxf(px2-px1, 1e-6f), ph = fmaxf(py2-py1, 1e-6f);
        float pcx = px1 + 0.5f*pw, pcy = py1 + 0.5f*ph;
        float wx, wy, ww, wh;
        if (stage == 0)      { wx=0.1f;   wy=0.1f;   ww=0.2f;   wh=0.2f;   }
        else if (stage == 1) { wx=0.05f;  wy=0.05f;  ww=0.1f;   wh=0.1f;   }
        else                 { wx=0.033f; wy=0.033f; ww=0.067f; wh=0.067f; }
        float dx = lg[lr][81]*wx, dy = lg[lr][82]*wy;
        float dw = fminf(lg[lr][83]*ww, CLIPV);
        float dh = fminf(lg[lr][84]*wh, CLIPV);
        float cx = dx*pw + pcx, cy = dy*ph + pcy;
        float w = expf(dw)*pw, h = expf(dh)*ph;
        cur[row*4+0] = fminf(fmaxf(cx - 0.5f*w, 0.f), img);
        cur[row*4+1] = fminf(fmaxf(cy - 0.5f*h, 0.f), img);
        cur[row*4+2] = fminf(fmaxf(cx + 0.5f*w, 0.f), img);
        cur[row*4+3] = fminf(fmaxf(cy + 0.5f*h, 0.f), img);
    }
    if (write_probs) {
        if (j == 1) {
            float m = lg[lr][0];
            for (int c2 = 1; c2 < 81; ++c2) m = fmaxf(m, lg[lr][c2]);
            float s = 0.f;
            for (int c2 = 0; c2 < 81; ++c2) s += expf(lg[lr][c2] - m);
            lg[lr][88] = m; lg[lr][89] = s;
        }
        __syncthreads();
        if (j < 81)
            probs[(size_t)row*81 + j] = expf(lg[lr][j] - lg[lr][88]) / lg[lr][89];
    }
}

__global__ __launch_bounds__(256) void compact_kernel(
    const float* __restrict__ probs, const float* __restrict__ cur,
    const int* __restrict__ img_sz, int* __restrict__ cnt,
    float* __restrict__ cscore, float4* __restrict__ cbox, float4* __restrict__ cob,
    float* __restrict__ carea, int* __restrict__ clabel, int* __restrict__ coidx)
{
    int gid = blockIdx.x*256 + threadIdx.x;
    if (gid >= NB*CAND_PER_IMG) return;
    int b = gid / CAND_PER_IMG;
    int rem = gid - b*CAND_PER_IMG;
    int n = rem / 80;
    int cm = rem - n*80;
    int label = cm + 1;
    int r = b*NPROP + n;
    float s = probs[(size_t)r*81 + label];
    float b0 = cur[r*4+0], b1 = cur[r*4+1], b2 = cur[r*4+2], b3 = cur[r*4+3];
    if (s > 0.05f && (b2 - b0) >= 1.0f && (b3 - b1) >= 1.0f) {
        int pos = atomicAdd(&cnt[b], 1);
        int base = b*CAND_PER_IMG + pos;
        float img = (float)(*img_sz);
        float t = (float)label * (img + 2.0f);
        float o0 = b0+t, o1 = b1+t, o2 = b2+t, o3 = b3+t;
        cscore[base] = s;
        cbox[base] = make_float4(b0, b1, b2, b3);
        cob[base]  = make_float4(o0, o1, o2, o3);
        carea[base] = fmaxf(o2-o0, 0.f) * fmaxf(o3-o1, 0.f);
        clabel[base] = label;
        coidx[base] = n*80 + cm;   // reference flat order for argmax tie-break
    }
}

__global__ __launch_bounds__(256) void nms_kernel(
    const int* __restrict__ cnt, float* __restrict__ cscore,
    const float4* __restrict__ cbox, const float4* __restrict__ cob,
    const float* __restrict__ carea, const int* __restrict__ clabel,
    const int* __restrict__ coidx, float* __restrict__ out)
{
    int b = blockIdx.x;
    int tid = threadIdx.x;
    int M = cnt[b];
    int base0 = b*CAND_PER_IMG;
    __shared__ float rs[256]; __shared__ int ri[256]; __shared__ int rp[256];
    __shared__ float sel[5];
    for (int it = 0; it < 100; ++it) {
        float best = -1e30f; int bo = 0x7fffffff; int bp = -1;
        for (int jj = tid; jj < M; jj += 256) {
            float s = cscore[base0+jj];
            int oi = coidx[base0+jj];
            if (s > best || (s == best && oi < bo)) { best = s; bo = oi; bp = jj; }
        }
        rs[tid] = best; ri[tid] = bo; rp[tid] = bp;
        __syncthreads();
        for (int off = 128; off > 0; off >>= 1) {
            if (tid < off) {
                if (rs[tid+off] > rs[tid] ||
                    (rs[tid+off] == rs[tid] && ri[tid+off] < ri[tid])) {
                    rs[tid] = rs[tid+off]; ri[tid] = ri[tid+off]; rp[tid] = rp[tid+off];
                }
            }
            __syncthreads();
        }
        float ssel = rs[0]; int pos = rp[0];
        if (ssel > 0.0f) {
            if (tid == 0) {
                float4 bx = cbox[base0+pos];
                out[b*400 + it*4 + 0] = bx.x;
                out[b*400 + it*4 + 1] = bx.y;
                out[b*400 + it*4 + 2] = bx.z;
                out[b*400 + it*4 + 3] = bx.w;
                out[800  + b*100 + it] = ssel;
                out[1000 + b*100 + it] = (float)clabel[base0+pos];
                float4 ob = cob[base0+pos];
                sel[0] = ob.x; sel[1] = ob.y; sel[2] = ob.z; sel[3] = ob.w;
                sel[4] = carea[base0+pos];
                cscore[base0+pos] = -1.0f;
            }
            __syncthreads();
            float bi0 = sel[0], bi1 = sel[1], bi2 = sel[2], bi3 = sel[3], ai = sel[4];
            for (int jj = tid; jj < M; jj += 256) {
                float4 ob = cob[base0+jj];
                float ix1 = fmaxf(bi0, ob.x), iy1 = fmaxf(bi1, ob.y);
                float ix2 = fminf(bi2, ob.z), iy2 = fminf(bi3, ob.w);
                float inter = fmaxf(ix2-ix1, 0.f) * fmaxf(iy2-iy1, 0.f);
                float iou = inter / (ai + carea[base0+jj] - inter + 1e-9f);
                if (iou > 0.5f) cscore[base0+jj] = -1.0f;
            }
        } else {
            if (tid == 0) {
                out[b*400+it*4+0] = 0.f; out[b*400+it*4+1] = 0.f;
                out[b*400+it*4+2] = 0.f; out[b*400+it*4+3] = 0.f;
                out[800 + b*100 + it] = 0.f;
                out[1000 + b*100 + it] = 0.f;
            }
        }
        __syncthreads();
    }
}

extern "C" void kernel_launch(void* const* d_in, const int* in_sizes, int n_in,
                              void* d_out, int out_size, void* d_ws, size_t ws_size,
                              hipStream_t stream)
{
    const float* features  = (const float*)d_in[0];
    const float* proposals = (const float*)d_in[1];
    const float* fc1_w = (const float*)d_in[2];
    const float* fc1_b = (const float*)d_in[3];
    const float* fc2_w = (const float*)d_in[4];
    const float* fc2_b = (const float*)d_in[5];
    const float* cls_w = (const float*)d_in[6];
    const float* cls_b = (const float*)d_in[7];
    const float* bbox_w = (const float*)d_in[8];
    const float* bbox_b = (const float*)d_in[9];
    const int* img_sz = (const int*)d_in[10];
    float* out = (float*)d_out;
    char* ws = (char*)d_ws;
    float*  X      = (float*) (ws + X_OFF);
    float*  h1     = (float*) (ws + H1_OFF);
    float*  h2     = (float*) (ws + H2_OFF);
    float*  probs  = (float*) (ws + PROBS_OFF);
    float*  cur    = (float*) (ws + CUR_OFF);
    int*    cnt    = (int*)   (ws + CNT_OFF);
    float*  cscore = (float*) (ws + CS_OFF);
    float4* cbox   = (float4*)(ws + CBX_OFF);
    float4* cob    = (float4*)(ws + COB_OFF);
    float*  carea  = (float*) (ws + CAR_OFF);
    int*    clabel = (int*)   (ws + CLB_OFF);
    int*    coidx  = (int*)   (ws + CIX_OFF);

    init_kernel<<<1, 64, 0, stream>>>(cnt);
    hipMemcpyAsync(cur, proposals, (size_t)NROWS*4*sizeof(float),
                   hipMemcpyDeviceToDevice, stream);

    dim3 g1(HID/64, NROWS/64);   // (16,16)
    for (int st = 0; st < 3; ++st) {
        roi_align_kernel<<<NROWS, 256, 0, stream>>>(features, cur, X);
        sgemm_bias_relu<<<g1, 256, 0, stream>>>(
            X, fc1_w + (size_t)st*INDIM*HID, fc1_b + st*HID, h1, INDIM, HID, 1);
        sgemm_bias_relu<<<g1, 256, 0, stream>>>(
            h1, fc2_w + (size_t)st*HID*HID, fc2_b + st*HID, h2, HID, HID, 1);
        heads_kernel<<<NROWS/4, 512, 0, stream>>>(
            h2, cls_w + (size_t)st*HID*NCLS, cls_b + st*NCLS,
            bbox_w + (size_t)st*HID*4, bbox_b + st*4,
            cur, probs, img_sz, st, st == 2 ? 1 : 0);
    }
    compact_kernel<<<(NB*CAND_PER_IMG)/256, 256, 0, stream>>>(
        probs, cur, img_sz, cnt, cscore, cbox, cob, carea, clabel, coidx);
    nms_kernel<<<NB, 256, 0, stream>>>(
        cnt, cscore, cbox, cob, carea, clabel, coidx, out);
}

// Round 2
// 867.640 us; speedup vs baseline: 2.4841x; 2.4841x over previous
//
#include <hip/hip_runtime.h>
#include <math.h>

#define NPROP 512
#define NB 2
#define NROWS (NB*NPROP)          // 1024
#define FCH 256
#define FH 64
#define FW 64
#define INDIM (FCH*7*7)           // 12544
#define HID 1024
#define NCLS 81
#define CAND_PER_IMG (NPROP*(NCLS-1))  // 40960
#define CLIPV 4.1351666f          // log(1000/16) rounded to f32

typedef _Float16 f16x8 __attribute__((ext_vector_type(8)));
typedef float f32x4 __attribute__((ext_vector_type(4)));

// ---- workspace layout (bytes) ----
#define X_OFF      0ull
#define H1_OFF     (X_OFF + (size_t)NROWS*INDIM*4)
#define H2_OFF     (H1_OFF + (size_t)NROWS*HID*4)
#define PROBS_OFF  (H2_OFF + (size_t)NROWS*HID*4)
#define CUR_OFF    (PROBS_OFF + (size_t)NROWS*NCLS*4)
#define CNT_OFF    (CUR_OFF + (size_t)NROWS*4*4)
#define CS_OFF     (CNT_OFF + 256)
#define CBX_OFF    (CS_OFF  + (size_t)NB*CAND_PER_IMG*4)
#define COB_OFF    (CBX_OFF + (size_t)NB*CAND_PER_IMG*16)
#define CAR_OFF    (COB_OFF + (size_t)NB*CAND_PER_IMG*16)
#define CLB_OFF    (CAR_OFF + (size_t)NB*CAND_PER_IMG*4)
#define CIX_OFF    (CLB_OFF + (size_t)NB*CAND_PER_IMG*4)
#define PART_OFF   (CIX_OFF + (size_t)NB*CAND_PER_IMG*4)
// PART: up to 8 planes of 1024x1024 fp32 = 32 MB

__global__ void init_kernel(int* cnt) {
    if (threadIdx.x < 2) cnt[threadIdx.x] = 0;
}

// one block per (b,n) proposal; 256 threads cover 256ch x 49 positions
__global__ __launch_bounds__(256) void roi_align_kernel(
    const float* __restrict__ feat, const float* __restrict__ boxes,
    float* __restrict__ X)
{
    int r = blockIdx.x;           // b*512+n
    int b = r >> 9;
    const float* f = feat + (size_t)b * (FCH*FH*FW);
    __shared__ float sb[4];
    __shared__ int   sx0[49], sx1[49], sy0[49], sy1[49];
    __shared__ float sw00[49], sw01[49], sw10[49], sw11[49];
    int tid = threadIdx.x;
    if (tid == 0) {
        float x1 = boxes[r*4+0]*0.125f, y1 = boxes[r*4+1]*0.125f;
        float x2 = boxes[r*4+2]*0.125f, y2 = boxes[r*4+3]*0.125f;
        sb[0] = x1; sb[1] = y1;
        sb[2] = fmaxf(x2-x1, 1.0f) / 7.0f;   // bw
        sb[3] = fmaxf(y2-y1, 1.0f) / 7.0f;   // bh
    }
    __syncthreads();
    if (tid < 49) {
        int py = tid / 7, px = tid - py*7;
        float gx = sb[0] + ((float)px + 0.5f)*sb[2];
        float gy = sb[1] + ((float)py + 0.5f)*sb[3];
        gx = fminf(fmaxf(gx, 0.0f), 63.0f);
        gy = fminf(fmaxf(gy, 0.0f), 63.0f);
        float x0f = floorf(gx), y0f = floorf(gy);
        int x0 = (int)x0f, y0 = (int)y0f;
        sx0[tid] = x0; sy0[tid] = y0;
        sx1[tid] = min(x0+1, 63); sy1[tid] = min(y0+1, 63);
        float dx = gx - x0f, dy = gy - y0f;
        sw00[tid] = (1.0f-dy)*(1.0f-dx);
        sw01[tid] = (1.0f-dy)*dx;
        sw10[tid] = dy*(1.0f-dx);
        sw11[tid] = dy*dx;
    }
    __syncthreads();
    size_t xbase = (size_t)r * INDIM;
    for (int i = tid; i < INDIM; i += 256) {
        int c = i / 49;
        int p = i - c*49;
        const float* fc = f + c*(FH*FW);
        int r0 = sy0[p]*FW, r1 = sy1[p]*FW;
        float v = fc[r0 + sx0[p]]*sw00[p] + fc[r0 + sx1[p]]*sw01[p]
                + fc[r1 + sx0[p]]*sw10[p] + fc[r1 + sx1[p]]*sw11[p];
        X[xbase + i] = v;
    }
}

// ---------------------------------------------------------------------------
// MFMA split-K GEMM: C_partial[z] = A[M x K] @ B[K x 1024] (scaled fp16 limbs)
// A fp32 row-major, B fp32 row-major, partial fp32 [z][1024][1024].
// 128x128 tile, 256 thr = 4 waves (2x2), each wave 64x64 = 4x4 frags 16x16x32.
// 3-product limb split: (32A)hi*(64B)hi + (32A)hi*(64B)lo + (32A)lo*(64B)hi.
// ---------------------------------------------------------------------------
__global__ __launch_bounds__(256) void mfma_gemm_splitk(
    const float* __restrict__ A, const float* __restrict__ Bw,
    float* __restrict__ part, int K, int ksteps)
{
    __shared__ __align__(16) _Float16 lds[4][512][8];  // 0=Ahi 1=Alo 2=Bhi 3=Blo
    const int tid = threadIdx.x;
    const int lane = tid & 63;
    const int w = tid >> 6, wm = w >> 1, wn = w & 1;
    const int kg = lane >> 4, lr = lane & 15;
    const int g1 = tid >> 7, sr = tid & 127;
    const int row0 = blockIdx.y << 7, col0 = blockIdx.x << 7;
    const int kb0 = blockIdx.z * ksteps * 32;

    f32x4 acc[4][4];
#pragma unroll
    for (int i = 0; i < 4; ++i)
#pragma unroll
        for (int j = 0; j < 4; ++j) acc[i][j] = (f32x4){0.f, 0.f, 0.f, 0.f};

    float a16[16], b16[16];
    // prologue: load tile 0
    {
        const float* Ar = A + (size_t)(row0 + sr)*K + kb0 + g1*8;
        float4 p0 = *(const float4*)(Ar);
        float4 p1 = *(const float4*)(Ar + 4);
        float4 p2 = *(const float4*)(Ar + 16);
        float4 p3 = *(const float4*)(Ar + 20);
        a16[0]=p0.x; a16[1]=p0.y; a16[2]=p0.z; a16[3]=p0.w;
        a16[4]=p1.x; a16[5]=p1.y; a16[6]=p1.z; a16[7]=p1.w;
        a16[8]=p2.x; a16[9]=p2.y; a16[10]=p2.z; a16[11]=p2.w;
        a16[12]=p3.x; a16[13]=p3.y; a16[14]=p3.z; a16[15]=p3.w;
        const float* Bp = Bw + (size_t)(kb0 + g1*8)*HID + col0 + sr;
#pragma unroll
        for (int j = 0; j < 8; ++j) b16[j]   = Bp[(size_t)j*HID];
#pragma unroll
        for (int j = 0; j < 8; ++j) b16[8+j] = Bp[(size_t)(j+16)*HID];
    }

    for (int t = 0; t < ksteps; ++t) {
        // convert tile t to fp16 limbs (scaled)
        f16x8 ah0, al0, ah1, al1, bh0, bl0, bh1, bl1;
#pragma unroll
        for (int j = 0; j < 8; ++j) {
            float v = a16[j] * 32.0f;
            _Float16 hh = (_Float16)v;
            ah0[j] = hh; al0[j] = (_Float16)(v - (float)hh);
            v = a16[8+j] * 32.0f; hh = (_Float16)v;
            ah1[j] = hh; al1[j] = (_Float16)(v - (float)hh);
            v = b16[j] * 64.0f; hh = (_Float16)v;
            bh0[j] = hh; bl0[j] = (_Float16)(v - (float)hh);
            v = b16[8+j] * 64.0f; hh = (_Float16)v;
            bh1[j] = hh; bl1[j] = (_Float16)(v - (float)hh);
        }
        __syncthreads();   // prior iter's frag reads done before overwrite
        *reinterpret_cast<f16x8*>(&lds[0][tid][0])     = ah0;
        *reinterpret_cast<f16x8*>(&lds[1][tid][0])     = al0;
        *reinterpret_cast<f16x8*>(&lds[0][tid+256][0]) = ah1;
        *reinterpret_cast<f16x8*>(&lds[1][tid+256][0]) = al1;
        *reinterpret_cast<f16x8*>(&lds[2][tid][0])     = bh0;
        *reinterpret_cast<f16x8*>(&lds[3][tid][0])     = bl0;
        *reinterpret_cast<f16x8*>(&lds[2][tid+256][0]) = bh1;
        *reinterpret_cast<f16x8*>(&lds[3][tid+256][0]) = bl1;
        __syncthreads();   // writes visible
        if (t + 1 < ksteps) {   // prefetch tile t+1; overlaps MFMA below
            int kb = kb0 + (t+1)*32;
            const float* Ar = A + (size_t)(row0 + sr)*K + kb + g1*8;
            float4 p0 = *(const float4*)(Ar);
            float4 p1 = *(const float4*)(Ar + 4);
            float4 p2 = *(const float4*)(Ar + 16);
            float4 p3 = *(const float4*)(Ar + 20);
            a16[0]=p0.x; a16[1]=p0.y; a16[2]=p0.z; a16[3]=p0.w;
            a16[4]=p1.x; a16[5]=p1.y; a16[6]=p1.z; a16[7]=p1.w;
            a16[8]=p2.x; a16[9]=p2.y; a16[10]=p2.z; a16[11]=p2.w;
            a16[12]=p3.x; a16[13]=p3.y; a16[14]=p3.z; a16[15]=p3.w;
            const float* Bp = Bw + (size_t)(kb + g1*8)*HID + col0 + sr;
#pragma unroll
            for (int j = 0; j < 8; ++j) b16[j]   = Bp[(size_t)j*HID];
#pragma unroll
            for (int j = 0; j < 8; ++j) b16[8+j] = Bp[(size_t)(j+16)*HID];
        }
        // fragments
        f16x8 Ah[4], Al[4], Bh[4], Bl[4];
#pragma unroll
        for (int mi = 0; mi < 4; ++mi) {
            int s = kg*128 + wm*64 + mi*16 + lr;
            Ah[mi] = *reinterpret_cast<const f16x8*>(&lds[0][s][0]);
            Al[mi] = *reinterpret_cast<const f16x8*>(&lds[1][s][0]);
        }
#pragma unroll
        for (int ni = 0; ni < 4; ++ni) {
            int s = kg*128 + wn*64 + ni*16 + lr;
            Bh[ni] = *reinterpret_cast<const f16x8*>(&lds[2][s][0]);
            Bl[ni] = *reinterpret_cast<const f16x8*>(&lds[3][s][0]);
        }
#pragma unroll
        for (int mi = 0; mi < 4; ++mi)
#pragma unroll
            for (int ni = 0; ni < 4; ++ni) {
                acc[mi][ni] = __builtin_amdgcn_mfma_f32_16x16x32_f16(Ah[mi], Bh[ni], acc[mi][ni], 0, 0, 0);
                acc[mi][ni] = __builtin_amdgcn_mfma_f32_16x16x32_f16(Ah[mi], Bl[ni], acc[mi][ni], 0, 0, 0);
                acc[mi][ni] = __builtin_amdgcn_mfma_f32_16x16x32_f16(Al[mi], Bh[ni], acc[mi][ni], 0, 0, 0);
            }
    }

    // epilogue: write fp32 partials. C/D layout: col=lane&15, row=(lane>>4)*4+j
    float* base = part + ((size_t)blockIdx.z << 20)
                + (size_t)row0*HID + col0 + wn*64 + lr;
#pragma unroll
    for (int mi = 0; mi < 4; ++mi) {
#pragma unroll
        for (int j = 0; j < 4; ++j) {
            int row = wm*64 + mi*16 + kg*4 + j;
            float* pr = base + (size_t)row*HID;
            pr[0]  = acc[mi][0][j];
            pr[16] = acc[mi][1][j];
            pr[32] = acc[mi][2][j];
            pr[48] = acc[mi][3][j];
        }
    }
}

// out[r][c] = relu(sum_p part[p][r][c] / 2048 + bias[c]); fixed order = deterministic
__global__ __launch_bounds__(256) void reduce_bias_relu(
    const float* __restrict__ part, const float* __restrict__ bias,
    float* __restrict__ out, int nsplit)
{
    int gid = blockIdx.x*256 + threadIdx.x;
    float s = 0.f;
    for (int p = 0; p < nsplit; ++p) s += part[((size_t)p << 20) + gid];
    s = s * (1.0f/2048.0f) + bias[gid & (HID-1)];
    out[gid] = fmaxf(s, 0.f);
}

// cls+bbox heads + decode (+softmax at last stage). 4 rows per block.
__global__ __launch_bounds__(512) void heads_kernel(
    const float* __restrict__ X, const float* __restrict__ cw, const float* __restrict__ cb,
    const float* __restrict__ bwt, const float* __restrict__ bbb,
    float* __restrict__ cur, float* __restrict__ probs,
    const int* __restrict__ img_sz, int stage, int write_probs)
{
    __shared__ float xs[4][1024];
    __shared__ float lg[4][96];
    int tid = threadIdx.x;
    int lr = tid >> 7;           // local row 0..3
    int j  = tid & 127;
    int row0 = blockIdx.x * 4;
    for (int i = tid; i < 4096; i += 512)
        xs[i >> 10][i & 1023] = X[(size_t)(row0 + (i >> 10))*1024 + (i & 1023)];
    __syncthreads();
    int row = row0 + lr;
    if (j < 81) {
        float acc = cb[j];
#pragma unroll 8
        for (int k = 0; k < 1024; ++k) acc = fmaf(xs[lr][k], cw[k*81 + j], acc);
        lg[lr][j] = acc;
    } else if (j < 85) {
        int jb = j - 81;
        float acc = bbb[jb];
#pragma unroll 8
        for (int k = 0; k < 1024; ++k) acc = fmaf(xs[lr][k], bwt[k*4 + jb], acc);
        lg[lr][j] = acc;
    }
    __syncthreads();
    if (j == 0) {   // box decode + clip
        float img = (float)(*img_sz);
        float px1 = cur[row*4+0], py1 = cur[row*4+1];
        float px2 = cur[row*4+2], py2 = cur[row*4+3];
        float pw = fmaxf(px2-px1, 1e-6f), ph = fmaxf(py2-py1, 1e-6f);
        float pcx = px1 + 0.5f*pw, pcy = py1 + 0.5f*ph;
        float wx, wy, ww, wh;
        if (stage == 0)      { wx=0.1f;   wy=0.1f;   ww=0.2f;   wh=0.2f;   }
        else if (stage == 1) { wx=0.05f;  wy=0.05f;  ww=0.1f;   wh=0.1f;   }
        else                 { wx=0.033f; wy=0.033f; ww=0.067f; wh=0.067f; }
        float dx = lg[lr][81]*wx, dy = lg[lr][82]*wy;
        float dw = fminf(lg[lr][83]*ww, CLIPV);
        float dh = fminf(lg[lr][84]*wh, CLIPV);
        float cx = dx*pw + pcx, cy = dy*ph + pcy;
        float w = expf(dw)*pw, h = expf(dh)*ph;
        cur[row*4+0] = fminf(fmaxf(cx - 0.5f*w, 0.f), img);
        cur[row*4+1] = fminf(fmaxf(cy - 0.5f*h, 0.f), img);
        cur[row*4+2] = fminf(fmaxf(cx + 0.5f*w, 0.f), img);
        cur[row*4+3] = fminf(fmaxf(cy + 0.5f*h, 0.f), img);
    }
    if (write_probs) {
        if (j == 1) {
            float m = lg[lr][0];
            for (int c2 = 1; c2 < 81; ++c2) m = fmaxf(m, lg[lr][c2]);
            float s = 0.f;
            for (int c2 = 0; c2 < 81; ++c2) s += expf(lg[lr][c2] - m);
            lg[lr][88] = m; lg[lr][89] = s;
        }
        __syncthreads();
        if (j < 81)
            probs[(size_t)row*81 + j] = expf(lg[lr][j] - lg[lr][88]) / lg[lr][89];
    }
}

__global__ __launch_bounds__(256) void compact_kernel(
    const float* __restrict__ probs, const float* __restrict__ cur,
    const int* __restrict__ img_sz, int* __restrict__ cnt,
    float* __restrict__ cscore, float4* __restrict__ cbox, float4* __restrict__ cob,
    float* __restrict__ carea, int* __restrict__ clabel, int* __restrict__ coidx)
{
    int gid = blockIdx.x*256 + threadIdx.x;
    if (gid >= NB*CAND_PER_IMG) return;
    int b = gid / CAND_PER_IMG;
    int rem = gid - b*CAND_PER_IMG;
    int n = rem / 80;
    int cm = rem - n*80;
    int label = cm + 1;
    int r = b*NPROP + n;
    float s = probs[(size_t)r*81 + label];
    float b0 = cur[r*4+0], b1 = cur[r*4+1], b2 = cur[r*4+2], b3 = cur[r*4+3];
    if (s > 0.05f && (b2 - b0) >= 1.0f && (b3 - b1) >= 1.0f) {
        int pos = atomicAdd(&cnt[b], 1);
        int base = b*CAND_PER_IMG + pos;
        float img = (float)(*img_sz);
        float t = (float)label * (img + 2.0f);
        float o0 = b0+t, o1 = b1+t, o2 = b2+t, o3 = b3+t;
        cscore[base] = s;
        cbox[base] = make_float4(b0, b1, b2, b3);
        cob[base]  = make_float4(o0, o1, o2, o3);
        carea[base] = fmaxf(o2-o0, 0.f) * fmaxf(o3-o1, 0.f);
        clabel[base] = label;
        coidx[base] = n*80 + cm;   // reference flat order for argmax tie-break
    }
}

__global__ __launch_bounds__(256) void nms_kernel(
    const int* __restrict__ cnt, float* __restrict__ cscore,
    const float4* __restrict__ cbox, const float4* __restrict__ cob,
    const float* __restrict__ carea, const int* __restrict__ clabel,
    const int* __restrict__ coidx, float* __restrict__ out)
{
    int b = blockIdx.x;
    int tid = threadIdx.x;
    int M = cnt[b];
    int base0 = b*CAND_PER_IMG;
    __shared__ float rs[256]; __shared__ int ri[256]; __shared__ int rp[256];
    __shared__ float sel[5];
    for (int it = 0; it < 100; ++it) {
        float best = -1e30f; int bo = 0x7fffffff; int bp = -1;
        for (int jj = tid; jj < M; jj += 256) {
            float s = cscore[base0+jj];
            int oi = coidx[base0+jj];
            if (s > best || (s == best && oi < bo)) { best = s; bo = oi; bp = jj; }
        }
        rs[tid] = best; ri[tid] = bo; rp[tid] = bp;
        __syncthreads();
        for (int off = 128; off > 0; off >>= 1) {
            if (tid < off) {
                if (rs[tid+off] > rs[tid] ||
                    (rs[tid+off] == rs[tid] && ri[tid+off] < ri[tid])) {
                    rs[tid] = rs[tid+off]; ri[tid] = ri[tid+off]; rp[tid] = rp[tid+off];
                }
            }
            __syncthreads();
        }
        float ssel = rs[0]; int pos = rp[0];
        if (ssel > 0.0f) {
            if (tid == 0) {
                float4 bx = cbox[base0+pos];
                out[b*400 + it*4 + 0] = bx.x;
                out[b*400 + it*4 + 1] = bx.y;
                out[b*400 + it*4 + 2] = bx.z;
                out[b*400 + it*4 + 3] = bx.w;
                out[800  + b*100 + it] = ssel;
                out[1000 + b*100 + it] = (float)clabel[base0+pos];
                float4 ob = cob[base0+pos];
                sel[0] = ob.x; sel[1] = ob.y; sel[2] = ob.z; sel[3] = ob.w;
                sel[4] = carea[base0+pos];
                cscore[base0+pos] = -1.0f;
            }
            __syncthreads();
            float bi0 = sel[0], bi1 = sel[1], bi2 = sel[2], bi3 = sel[3], ai = sel[4];
            for (int jj = tid; jj < M; jj += 256) {
                float4 ob = cob[base0+jj];
                float ix1 = fmaxf(bi0, ob.x), iy1 = fmaxf(bi1, ob.y);
                float ix2 = fminf(bi2, ob.z), iy2 = fminf(bi3, ob.w);
                float inter = fmaxf(ix2-ix1, 0.f) * fmaxf(iy2-iy1, 0.f);
                float iou = inter / (ai + carea[base0+jj] - inter + 1e-9f);
                if (iou > 0.5f) cscore[base0+jj] = -1.0f;
            }
        } else {
            if (tid == 0) {
                out[b*400+it*4+0] = 0.f; out[b*400+it*4+1] = 0.f;
                out[b*400+it*4+2] = 0.f; out[b*400+it*4+3] = 0.f;
                out[800 + b*100 + it] = 0.f;
                out[1000 + b*100 + it] = 0.f;
            }
        }
        __syncthreads();
    }
}

extern "C" void kernel_launch(void* const* d_in, const int* in_sizes, int n_in,
                              void* d_out, int out_size, void* d_ws, size_t ws_size,
                              hipStream_t stream)
{
    const float* features  = (const float*)d_in[0];
    const float* proposals = (const float*)d_in[1];
    const float* fc1_w = (const float*)d_in[2];
    const float* fc1_b = (const float*)d_in[3];
    const float* fc2_w = (const float*)d_in[4];
    const float* fc2_b = (const float*)d_in[5];
    const float* cls_w = (const float*)d_in[6];
    const float* cls_b = (const float*)d_in[7];
    const float* bbox_w = (const float*)d_in[8];
    const float* bbox_b = (const float*)d_in[9];
    const int* img_sz = (const int*)d_in[10];
    float* out = (float*)d_out;
    char* ws = (char*)d_ws;
    float*  X      = (float*) (ws + X_OFF);
    float*  h1     = (float*) (ws + H1_OFF);
    float*  h2     = (float*) (ws + H2_OFF);
    float*  probs  = (float*) (ws + PROBS_OFF);
    float*  cur    = (float*) (ws + CUR_OFF);
    int*    cnt    = (int*)   (ws + CNT_OFF);
    float*  cscore = (float*) (ws + CS_OFF);
    float4* cbox   = (float4*)(ws + CBX_OFF);
    float4* cob    = (float4*)(ws + COB_OFF);
    float*  carea  = (float*) (ws + CAR_OFF);
    int*    clabel = (int*)   (ws + CLB_OFF);
    int*    coidx  = (int*)   (ws + CIX_OFF);
    float*  part   = (float*) (ws + PART_OFF);

    init_kernel<<<1, 64, 0, stream>>>(cnt);
    hipMemcpyAsync(cur, proposals, (size_t)NROWS*4*sizeof(float),
                   hipMemcpyDeviceToDevice, stream);

    for (int st = 0; st < 3; ++st) {
        roi_align_kernel<<<NROWS, 256, 0, stream>>>(features, cur, X);
        // fc1: K=12544, split-K 8 x 49 steps
        mfma_gemm_splitk<<<dim3(8, 8, 8), 256, 0, stream>>>(
            X, fc1_w + (size_t)st*INDIM*HID, part, INDIM, 49);
        reduce_bias_relu<<<(NROWS*HID)/256, 256, 0, stream>>>(
            part, fc1_b + st*HID, h1, 8);
        // fc2: K=1024, split-K 4 x 8 steps
        mfma_gemm_splitk<<<dim3(8, 8, 4), 256, 0, stream>>>(
            h1, fc2_w + (size_t)st*HID*HID, part, HID, 8);
        reduce_bias_relu<<<(NROWS*HID)/256, 256, 0, stream>>>(
            part, fc2_b + st*HID, h2, 4);
        heads_kernel<<<NROWS/4, 512, 0, stream>>>(
            h2, cls_w + (size_t)st*HID*NCLS, cls_b + st*NCLS,
            bbox_w + (size_t)st*HID*4, bbox_b + st*4,
            cur, probs, img_sz, st, st == 2 ? 1 : 0);
    }
    compact_kernel<<<(NB*CAND_PER_IMG)/256, 256, 0, stream>>>(
        probs, cur, img_sz, cnt, cscore, cbox, cob, carea, clabel, coidx);
    nms_kernel<<<NB, 256, 0, stream>>>(
        cnt, cscore, cbox, cob, carea, clabel, coidx, out);
}